// Round 14
// baseline (435.151 us; speedup 1.0000x reference)
//
#include <hip/hip_runtime.h>
#include <hip/hip_bf16.h>
#include <string.h>

typedef __attribute__((ext_vector_type(8))) short short8;
typedef __attribute__((ext_vector_type(4))) float f32x4;
typedef unsigned long long ull;

#define NN 50000
#define NE 600000
#define GXc 782    // ceil(50000/64)
#define ABc 12500  // agg128: 4 nodes/block
#define AB64 6250  // agg64: 8 nodes/block
#define NBUK 196
#define NEB 128
#define CHK 4688

__device__ __forceinline__ unsigned short f32_bf16(float f) {
  unsigned u = __float_as_uint(f);
  unsigned r = u + 0x7FFFu + ((u >> 16) & 1u);
  return (unsigned short)(r >> 16);
}
__device__ __forceinline__ float bf_lo(unsigned v) { return __uint_as_float(v << 16); }
__device__ __forceinline__ float bf_hi(unsigned v) { return __uint_as_float(v & 0xFFFF0000u); }

// ---------------- fused transpose of all 7 weights ----------------
// tiled=1 (G1 weights): dst elem = (k>>5)*4096 + n*32 + (k&31)   [tile-contiguous 128x32]
struct TransDesc { const float* src; unsigned short* dst; int K, Nn, Kpad, base, tiled; };
struct TransArgs { TransDesc d[7]; int total; };

__global__ void transpose_all_kernel(TransArgs a) {
  int idx = blockIdx.x * 256 + threadIdx.x;
  if (idx >= a.total) return;
  int s = 0;
#pragma unroll
  for (int q = 1; q < 7; ++q)
    if (idx >= a.d[q].base) s = q;
  TransDesc t = a.d[s];
  int off = idx - t.base;
  int n = off / t.Kpad, k = off % t.Kpad;
  float v = (k < t.K) ? t.src[(size_t)k * t.Nn + n] : 0.f;
  if (t.tiled)
    t.dst[(size_t)(k >> 5) * 4096 + n * 32 + (k & 31)] = f32_bf16(v);
  else
    t.dst[off] = f32_bf16(v);
}

// ---------- G1 GEMM: DMA-staged (global_load_lds), BK=32, LDS double-buffer ----------
// LDS map (dynamic, 32 KB): AsF f32 [2][64][32] at 0 (2x8KB); Bs bf16 [2][128][32] at 16384.
__device__ __forceinline__ void gemm1_dma_body(char* lds, const float* __restrict__ A,
                                               const unsigned short* __restrict__ BT,
                                               unsigned short* __restrict__ C, int M, int K,
                                               int Kpad, int bx) {
  const int tid = threadIdx.x;
  const int m0 = bx * 64;
  const int wave = tid >> 6, lane = tid & 63;
  const int wr = wave >> 1, wc = wave & 1;
  const int rowbase = wr * 32, colbase = wc * 64;
  const int lrow = lane & 15, lk = lane >> 4;
  const bool lastBlk = (m0 + 64 > M);
  const int nt = Kpad >> 5;

  char* AsBase = lds;
  char* BsBase = lds + 16384;

  f32x4 acc[2][4] = {};

  auto stage = [&](int b, int kt) {
    if (!lastBlk) {
#pragma unroll
      for (int p = 0; p < 2; ++p) {
        int o = wave * 1024 + p * 4096 + lane * 16;
        int row = o >> 7;
        int g = (o >> 4) & 7;
        int scb = kt * 128 + ((g ^ (row & 7)) << 4);
        const char* gp = (const char*)(A + (size_t)(m0 + row) * K) + scb;
        char* lp = AsBase + b * 8192 + wave * 1024 + p * 4096;
        __builtin_amdgcn_global_load_lds((const __attribute__((address_space(1))) void*)gp,
                                         (__attribute__((address_space(3))) void*)lp, 16, 0, 0);
      }
#pragma unroll
      for (int p = 0; p < 2; ++p) {
        int o = wave * 1024 + p * 4096 + lane * 16;
        const char* gp = (const char*)BT + (size_t)kt * 8192 + o;
        char* lp = BsBase + b * 8192 + wave * 1024 + p * 4096;
        __builtin_amdgcn_global_load_lds((const __attribute__((address_space(1))) void*)gp,
                                         (__attribute__((address_space(3))) void*)lp, 16, 0, 0);
      }
    } else {
      // guarded register path (only the final row-block)
#pragma unroll
      for (int p = 0; p < 2; ++p) {
        int o = wave * 1024 + p * 4096 + lane * 16;
        int row = o >> 7;
        int g = (o >> 4) & 7;
        int c0 = kt * 32 + ((g ^ (row & 7)) << 2);
        int gr = m0 + row;
        float4 v = make_float4(0.f, 0.f, 0.f, 0.f);
        if (gr < M) {
          const float* sp = A + (size_t)gr * K + c0;
          if (c0 + 4 <= K) {
            v = *(const float4*)sp;
          } else {
            if (c0 + 0 < K) v.x = sp[0];
            if (c0 + 1 < K) v.y = sp[1];
            if (c0 + 2 < K) v.z = sp[2];
            if (c0 + 3 < K) v.w = sp[3];
          }
        }
        *(float4*)(AsBase + b * 8192 + o) = v;
      }
#pragma unroll
      for (int p = 0; p < 2; ++p) {
        int o = wave * 1024 + p * 4096 + lane * 16;
        short8 bv = *(const short8*)((const char*)BT + (size_t)kt * 8192 + o);
        *(short8*)(BsBase + b * 8192 + o) = bv;
      }
    }
  };

  auto computeT = [&](int b) {
    short8 af[2], bfj[4];
#pragma unroll
    for (int i = 0; i < 2; ++i) {
      int row = rowbase + i * 16 + lrow;
      int r7 = row & 7;
      int g0 = (lk * 2 + 0) ^ r7;
      int g1 = (lk * 2 + 1) ^ r7;
      float4 a0 = *(const float4*)(AsBase + b * 8192 + row * 128 + (g0 << 4));
      float4 a1 = *(const float4*)(AsBase + b * 8192 + row * 128 + (g1 << 4));
      unsigned w0 = (unsigned)f32_bf16(a0.x) | ((unsigned)f32_bf16(a0.y) << 16);
      unsigned w1 = (unsigned)f32_bf16(a0.z) | ((unsigned)f32_bf16(a0.w) << 16);
      unsigned w2 = (unsigned)f32_bf16(a1.x) | ((unsigned)f32_bf16(a1.y) << 16);
      unsigned w3 = (unsigned)f32_bf16(a1.z) | ((unsigned)f32_bf16(a1.w) << 16);
      uint4 uu = make_uint4(w0, w1, w2, w3);
      af[i] = *reinterpret_cast<short8*>(&uu);
    }
#pragma unroll
    for (int j = 0; j < 4; ++j) {
      int n = colbase + j * 16 + lrow;
      bfj[j] = *(const short8*)(BsBase + b * 8192 + n * 64 + lk * 16);
    }
#pragma unroll
    for (int i = 0; i < 2; ++i)
#pragma unroll
      for (int j = 0; j < 4; ++j)
        acc[i][j] = __builtin_amdgcn_mfma_f32_16x16x32_bf16(af[i], bfj[j], acc[i][j], 0, 0, 0);
  };

  stage(0, 0);
  __syncthreads();
  for (int kt = 0; kt < nt; ++kt) {
    int b = kt & 1;
    if (kt + 1 < nt) stage(b ^ 1, kt + 1);
    computeT(b);
    __syncthreads();
  }

#pragma unroll
  for (int i = 0; i < 2; ++i)
#pragma unroll
    for (int j = 0; j < 4; ++j)
#pragma unroll
      for (int q = 0; q < 4; ++q) {
        int row = m0 + rowbase + i * 16 + lk * 4 + q;
        int col = colbase + j * 16 + lrow;
        if (row < M) C[(size_t)row * 128 + col] = f32_bf16(acc[i][j][q]);
      }
}

// ---------- old register-staged GEMM body (kept for gemm2 / fuse, ABF16 path) ----------
template <int BN, bool PRED>
__device__ __forceinline__ void gemm_body(char* ldsraw, const unsigned short* __restrict__ Ah,
                                          const unsigned short* __restrict__ BT,
                                          unsigned short* __restrict__ C, int M, int K, int Kpad,
                                          int ldc, const float* fbias, const float* Wp,
                                          const float* bp, float* pout, int bx) {
  constexpr int BM = 64, BK = 64, LW = BK + 8;
  unsigned short* As = (unsigned short*)ldsraw;
  unsigned short* Bs = As + BM * LW;
  const int tid = threadIdx.x;
  const int m0 = bx * BM;
  const int wid = tid >> 6, lane = tid & 63;
  constexpr int FM = 1;
  constexpr int FN = 4;
  const int rowbase = wid * 16, colbase = 0;
  const int lrow = lane & 15, lk = lane >> 4;

  f32x4 acc[FM][FN] = {};
  short8 arh0[2], arh1[2];
  short8 brr0[BN / 32], brr1[BN / 32];

  const int nt = Kpad / BK;

  auto loadA = [&](auto& arhX, int k0) {
#pragma unroll
    for (int p = 0; p < 2; ++p) {
      int f = tid + p * 256;
      int row = f >> 3, c8 = f & 7;
      int gr = m0 + row;
      if (gr >= M) gr = M - 1;
      arhX[p] = *(const short8*)(Ah + (size_t)gr * K + k0 + c8 * 8);
    }
  };
  auto loadB = [&](auto& brrX, int k0) {
#pragma unroll
    for (int p = 0; p < BN / 32; ++p) {
      int f = tid + p * 256;
      int n = f >> 3, c8 = f & 7;
      brrX[p] = *(const short8*)(BT + (size_t)n * Kpad + k0 + c8 * 8);
    }
  };
  auto storeAB = [&](auto& arhX, auto& brrX) {
#pragma unroll
    for (int p = 0; p < 2; ++p) {
      int f = tid + p * 256;
      int row = f >> 3, c8 = f & 7;
      *reinterpret_cast<short8*>(&As[row * LW + c8 * 8]) = arhX[p];
    }
#pragma unroll
    for (int p = 0; p < BN / 32; ++p) {
      int f = tid + p * 256;
      int n = f >> 3, c8 = f & 7;
      *reinterpret_cast<short8*>(&Bs[n * LW + c8 * 8]) = brrX[p];
    }
  };
  auto compute = [&]() {
#pragma unroll
    for (int ks = 0; ks < 2; ++ks) {
      short8 af[FM], bfj[FN];
#pragma unroll
      for (int i = 0; i < FM; ++i)
        af[i] = *reinterpret_cast<const short8*>(
            &As[(rowbase + i * 16 + lrow) * LW + ks * 32 + lk * 8]);
#pragma unroll
      for (int j = 0; j < FN; ++j)
        bfj[j] = *reinterpret_cast<const short8*>(
            &Bs[(colbase + j * 16 + lrow) * LW + ks * 32 + lk * 8]);
#pragma unroll
      for (int i = 0; i < FM; ++i)
#pragma unroll
        for (int j = 0; j < FN; ++j)
          acc[i][j] = __builtin_amdgcn_mfma_f32_16x16x32_bf16(af[i], bfj[j], acc[i][j], 0, 0, 0);
    }
  };

  loadA(arh0, 0);
  loadB(brr0, 0);
  if (nt > 1) {
    loadA(arh1, BK);
    loadB(brr1, BK);
  }
  for (int kt = 0; kt < nt; kt += 2) {
    if (kt) __syncthreads();
    storeAB(arh0, brr0);
    __syncthreads();
    if (kt + 2 < nt) {
      loadA(arh0, (kt + 2) * BK);
      loadB(brr0, (kt + 2) * BK);
    }
    compute();
    if (kt + 1 < nt) {
      __syncthreads();
      storeAB(arh1, brr1);
      __syncthreads();
      if (kt + 3 < nt) {
        loadA(arh1, (kt + 3) * BK);
        loadB(brr1, (kt + 3) * BK);
      }
      compute();
    }
  }

  if (PRED) {
    float p0[4] = {0.f, 0.f, 0.f, 0.f}, p1[4] = {0.f, 0.f, 0.f, 0.f};
#pragma unroll
    for (int j = 0; j < FN; ++j) {
      int col = j * 16 + lrow;
      float w0 = Wp[col * 2], w1 = Wp[col * 2 + 1];
      float fb = fbias[col];
#pragma unroll
      for (int q = 0; q < 4; ++q) {
        float v = fmaxf(acc[0][j][q] + fb, 0.f);
        p0[q] += v * w0;
        p1[q] += v * w1;
      }
    }
#pragma unroll
    for (int o = 1; o < 16; o <<= 1) {
#pragma unroll
      for (int q = 0; q < 4; ++q) {
        p0[q] += __shfl_xor(p0[q], o);
        p1[q] += __shfl_xor(p1[q], o);
      }
    }
    if (lrow == 0) {
#pragma unroll
      for (int q = 0; q < 4; ++q) {
        int row = m0 + rowbase + lk * 4 + q;
        if (row < M) {
          pout[(size_t)row * 2 + 0] = p0[q] + bp[0];
          pout[(size_t)row * 2 + 1] = p1[q] + bp[1];
        }
      }
    }
  } else {
#pragma unroll
    for (int i = 0; i < FM; ++i)
#pragma unroll
      for (int j = 0; j < FN; ++j)
#pragma unroll
        for (int q = 0; q < 4; ++q) {
          int row = m0 + rowbase + i * 16 + lk * 4 + q;
          int col = colbase + j * 16 + lrow;
          if (row < M) C[(size_t)row * ldc + col] = f32_bf16(acc[i][j][q]);
        }
  }
}

// ================= atomic-free CSR build (bodies) =================
struct BuildArgs {
  const int* ei[3];
  const float* ew[3];
  unsigned* blockHist;
  unsigned* cursors;
  unsigned* totals;
  unsigned* bucketBase;
  int2* part;
  int* off3;
  int* cnt3;
  float* dinv3;
  int2* csr;
};

__device__ void partA_body(const BuildArgs& a, int bx) {
  int b = bx / NEB, blk = bx % NEB;
  __shared__ unsigned h[NBUK];
  for (int j = threadIdx.x; j < NBUK; j += 256) h[j] = 0;
  __syncthreads();
  const int* __restrict__ dstp = a.ei[b] + NE;
  int e0 = blk * CHK, e1 = e0 + CHK;
  if (e1 > NE) e1 = NE;
  for (int e = e0 + (int)threadIdx.x; e < e1; e += 256)
    atomicAdd(&h[(unsigned)dstp[e] >> 8], 1u);
  __syncthreads();
  unsigned* out = a.blockHist + (size_t)(b * NEB + blk) * NBUK;
  for (int j = threadIdx.x; j < NBUK; j += 256) out[j] = h[j];
}

__global__ void partB1_kernel(BuildArgs a) {
  int b = blockIdx.x / NBUK, k = blockIdx.x % NBUK;
  __shared__ unsigned s[NEB];
  int t = threadIdx.x;
  unsigned v = a.blockHist[(size_t)(b * NEB + t) * NBUK + k];
  s[t] = v;
  __syncthreads();
  for (int o = 1; o < NEB; o <<= 1) {
    unsigned u = (t >= o) ? s[t - o] : 0;
    __syncthreads();
    s[t] += u;
    __syncthreads();
  }
  a.cursors[(size_t)(b * NEB + t) * NBUK + k] = s[t] - v;
  if (t == NEB - 1) a.totals[b * NBUK + k] = s[t];
}

__global__ void partB2_kernel(BuildArgs a) {
  int b = blockIdx.x;
  __shared__ unsigned s[256];
  int t = threadIdx.x;
  unsigned v = (t < NBUK) ? a.totals[b * NBUK + t] : 0;
  s[t] = v;
  __syncthreads();
  for (int o = 1; o < 256; o <<= 1) {
    unsigned u = (t >= o) ? s[t - o] : 0;
    __syncthreads();
    s[t] += u;
    __syncthreads();
  }
  if (t < NBUK) a.bucketBase[b * NBUK + t] = s[t] - v;
}

__device__ void partC_body(const BuildArgs& a, int bx) {
  int b = bx / NEB, blk = bx % NEB;
  __shared__ unsigned cur[NBUK];
  for (int j = threadIdx.x; j < NBUK; j += 256)
    cur[j] = a.cursors[(size_t)(b * NEB + blk) * NBUK + j] + a.bucketBase[b * NBUK + j];
  __syncthreads();
  const int* __restrict__ srcp = a.ei[b];
  const int* __restrict__ dstp = srcp + NE;
  const float* __restrict__ ewp = a.ew[b];
  int2* __restrict__ out = a.part + (size_t)b * NE;
  int e0 = blk * CHK, e1 = e0 + CHK;
  if (e1 > NE) e1 = NE;
  for (int e = e0 + (int)threadIdx.x; e < e1; e += 256) {
    int d = dstp[e], s = srcp[e];
    float w = ewp[e];
    unsigned k = (unsigned)d >> 8;
    unsigned pos = atomicAdd(&cur[k], 1u);
    out[pos] = make_int2((int)(((unsigned)(d & 255) << 24) | (unsigned)s), __float_as_int(w));
  }
}

__device__ void partD1_body(const BuildArgs& a, int bx) {
  int b = bx / NBUK, k = bx % NBUK;
  __shared__ unsigned cnt[256];
  __shared__ float ws[256];
  int t = threadIdx.x;
  cnt[t] = 0;
  ws[t] = 0.f;
  __syncthreads();
  unsigned base = a.bucketBase[b * NBUK + k];
  unsigned total = a.totals[b * NBUK + k];
  const int2* __restrict__ pp = a.part + (size_t)b * NE + base;
  for (unsigned t2 = threadIdx.x; t2 < total; t2 += 256) {
    int2 pr = pp[t2];
    unsigned dl = (unsigned)pr.x >> 24;
    atomicAdd(&cnt[dl], 1u);
    atomicAdd(&ws[dl], __int_as_float(pr.y));
  }
  __syncthreads();
  unsigned v = cnt[t];
  float wv = ws[t];
  for (int o = 1; o < 256; o <<= 1) {
    unsigned u = (t >= o) ? cnt[t - o] : 0;
    __syncthreads();
    cnt[t] += u;
    __syncthreads();
  }
  int node = k * 256 + t;
  if (node < NN) {
    a.off3[b * NN + node] = (int)(base + cnt[t] - v);
    a.cnt3[b * NN + node] = (int)v;
    a.dinv3[b * NN + node] = rsqrtf(wv + 1.0f);
  }
}

__device__ void partD2_body(const BuildArgs& a, int bx) {
  int b = bx / NBUK, k = bx % NBUK;
  __shared__ unsigned cur[256];
  int t = threadIdx.x;
  int node = k * 256 + t;
  cur[t] = (node < NN) ? (unsigned)a.off3[b * NN + node] : 0u;
  __syncthreads();
  unsigned base = a.bucketBase[b * NBUK + k];
  unsigned total = a.totals[b * NBUK + k];
  const int2* __restrict__ pp = a.part + (size_t)b * NE + base;
  const float* __restrict__ dinvb = a.dinv3 + (size_t)b * NN;
  int2* __restrict__ out = a.csr + (size_t)b * NE;
  for (unsigned t2 = threadIdx.x; t2 < total; t2 += 256) {
    int2 pr = pp[t2];
    unsigned dl = (unsigned)pr.x >> 24;
    int s = pr.x & 0xFFFFFF;
    float w = __int_as_float(pr.y);
    unsigned pos = atomicAdd(&cur[dl], 1u);
    int d = k * 256 + (int)dl;
    float cw = dinvb[s] * w * dinvb[d];
    out[pos] = make_int2(s, __float_as_int(cw));
  }
}

// ================= mega kernels: build stage + gemm1 slice =================
struct G1Args {
  const float* A[3];
  const unsigned short* B[3];
  unsigned short* C[3];
  int K[3], Kp[3];
};

__device__ __forceinline__ void g1_dispatch(char* lds, const G1Args& g, int id) {
  int slot = id / GXc, b2 = id - slot * GXc;
  gemm1_dma_body(lds, g.A[slot], g.B[slot], g.C[slot], NN, g.K[slot], g.Kp[slot], b2);
}

__global__ __launch_bounds__(256) void megaA_kernel(BuildArgs ba, G1Args g1, int nbld, int base) {
  extern __shared__ char lds[];
  int bx = blockIdx.x;
  if (bx < nbld) { partA_body(ba, bx); return; }
  g1_dispatch(lds, g1, base + bx - nbld);
}
__global__ __launch_bounds__(256) void megaC_kernel(BuildArgs ba, G1Args g1, int nbld, int base) {
  extern __shared__ char lds[];
  int bx = blockIdx.x;
  if (bx < nbld) { partC_body(ba, bx); return; }
  g1_dispatch(lds, g1, base + bx - nbld);
}
__global__ __launch_bounds__(256) void megaD1_kernel(BuildArgs ba, G1Args g1, int nbld, int base) {
  extern __shared__ char lds[];
  int bx = blockIdx.x;
  if (bx < nbld) { partD1_body(ba, bx); return; }
  g1_dispatch(lds, g1, base + bx - nbld);
}
__global__ __launch_bounds__(256) void megaD2_kernel(BuildArgs ba, G1Args g1, int nbld, int base) {
  extern __shared__ char lds[];
  int bx = blockIdx.x;
  if (bx < nbld) { partD2_body(ba, bx); return; }
  g1_dispatch(lds, g1, base + bx - nbld);
}

// ================= aggregation (depth-4 pipelined gathers) =================
struct AggArgs {
  const unsigned short* x[3];
  const float* bias[3];
  unsigned short* out[3];
  const float* dinv3;
  const int* cnt3;
  const int* off3;
  const int2* csr;
};

__global__ __launch_bounds__(256) void agg128x3_kernel(AggArgs a) {
  int bx = blockIdx.x;
  int slot = bx / ABc, t = bx - slot * ABc;
  int i = (t << 2) + ((int)threadIdx.x >> 6);
  if (i >= NN) return;
  int lane = threadIdx.x & 63;
  const unsigned short* x = a.x[slot];
  float di = a.dinv3[(size_t)slot * NN + i];
  unsigned sv = *(const unsigned*)(x + (size_t)i * 128 + lane * 2);
  float w0s = di * di;
  float acc0 = bf_lo(sv) * w0s, acc1 = bf_hi(sv) * w0s;
  int cnt = a.cnt3[(size_t)slot * NN + i];
  const int2* cp = a.csr + (size_t)slot * NE + a.off3[slot * NN + i];

  int np = cnt & ~3;
  int2 e[4];
  unsigned v[4];
  if (np > 0) {
#pragma unroll
    for (int q = 0; q < 4; ++q) e[q] = cp[q];
#pragma unroll
    for (int q = 0; q < 4; ++q)
      v[q] = *(const unsigned*)(x + (size_t)e[q].x * 128 + lane * 2);
  }
  for (int t2 = 0; t2 < np; t2 += 4) {
    int2 en[4];
    unsigned vn[4];
    if (t2 + 4 < np) {
#pragma unroll
      for (int q = 0; q < 4; ++q) en[q] = cp[t2 + 4 + q];
#pragma unroll
      for (int q = 0; q < 4; ++q)
        vn[q] = *(const unsigned*)(x + (size_t)en[q].x * 128 + lane * 2);
    }
#pragma unroll
    for (int q = 0; q < 4; ++q) {
      float wt = __int_as_float(e[q].y);
      acc0 += bf_lo(v[q]) * wt;
      acc1 += bf_hi(v[q]) * wt;
    }
#pragma unroll
    for (int q = 0; q < 4; ++q) {
      e[q] = en[q];
      v[q] = vn[q];
    }
  }
  for (int t2 = np; t2 < cnt; ++t2) {
    int2 s0 = cp[t2];
    unsigned v0 = *(const unsigned*)(x + (size_t)s0.x * 128 + lane * 2);
    float wa = __int_as_float(s0.y);
    acc0 += bf_lo(v0) * wa;
    acc1 += bf_hi(v0) * wa;
  }
  acc0 = fmaxf(acc0 + a.bias[slot][lane * 2], 0.f);
  acc1 = fmaxf(acc1 + a.bias[slot][lane * 2 + 1], 0.f);
  unsigned o = (unsigned)f32_bf16(acc0) | ((unsigned)f32_bf16(acc1) << 16);
  *(unsigned*)(a.out[slot] + (size_t)i * 128 + lane * 2) = o;
}

__global__ __launch_bounds__(256) void agg64x3_kernel(AggArgs a) {
  int bx = blockIdx.x;
  int slot = bx / AB64, t = bx - slot * AB64;
  int i = (t << 3) + ((int)threadIdx.x >> 5);
  if (i >= NN) return;
  int l2 = (threadIdx.x & 31) * 2;
  const unsigned short* x = a.x[slot];
  float di = a.dinv3[(size_t)slot * NN + i];
  unsigned sv = *(const unsigned*)(x + (size_t)i * 64 + l2);
  float w0s = di * di;
  float acc0 = bf_lo(sv) * w0s, acc1 = bf_hi(sv) * w0s;
  int cnt = a.cnt3[(size_t)slot * NN + i];
  const int2* cp = a.csr + (size_t)slot * NE + a.off3[slot * NN + i];

  int np = cnt & ~3;
  int2 e[4];
  unsigned v[4];
  if (np > 0) {
#pragma unroll
    for (int q = 0; q < 4; ++q) e[q] = cp[q];
#pragma unroll
    for (int q = 0; q < 4; ++q)
      v[q] = *(const unsigned*)(x + (size_t)e[q].x * 64 + l2);
  }
  for (int t2 = 0; t2 < np; t2 += 4) {
    int2 en[4];
    unsigned vn[4];
    if (t2 + 4 < np) {
#pragma unroll
      for (int q = 0; q < 4; ++q) en[q] = cp[t2 + 4 + q];
#pragma unroll
      for (int q = 0; q < 4; ++q)
        vn[q] = *(const unsigned*)(x + (size_t)en[q].x * 64 + l2);
    }
#pragma unroll
    for (int q = 0; q < 4; ++q) {
      float wt = __int_as_float(e[q].y);
      acc0 += bf_lo(v[q]) * wt;
      acc1 += bf_hi(v[q]) * wt;
    }
#pragma unroll
    for (int q = 0; q < 4; ++q) {
      e[q] = en[q];
      v[q] = vn[q];
    }
  }
  for (int t2 = np; t2 < cnt; ++t2) {
    int2 s0 = cp[t2];
    unsigned v0 = *(const unsigned*)(x + (size_t)s0.x * 64 + l2);
    float wa = __int_as_float(s0.y);
    acc0 += bf_lo(v0) * wa;
    acc1 += bf_hi(v0) * wa;
  }
  acc0 = fmaxf(acc0 + a.bias[slot][l2], 0.f);
  acc1 = fmaxf(acc1 + a.bias[slot][l2 + 1], 0.f);
  unsigned o = (unsigned)f32_bf16(acc0) | ((unsigned)f32_bf16(acc1) << 16);
  *(unsigned*)(a.out[0] + (size_t)i * 192 + slot * 64 + l2) = o;
}

struct G2Args {
  const unsigned short* A[3];
  const unsigned short* B[3];
  unsigned short* C[3];
};

__global__ __launch_bounds__(256) void gemm2x3_kernel(G2Args a) {
  extern __shared__ char lds[];
  int slot = blockIdx.x / GXc, b2 = blockIdx.x - slot * GXc;
  gemm_body<64, false>(lds, a.A[slot], a.B[slot], a.C[slot], NN, 128, 128, 64, nullptr, nullptr,
                       nullptr, nullptr, b2);
}

__global__ __launch_bounds__(256) void fuse_kernel(const unsigned short* __restrict__ comb,
                                                   const unsigned short* __restrict__ wft,
                                                   const float* __restrict__ fb,
                                                   const float* __restrict__ wp,
                                                   const float* __restrict__ bp,
                                                   float* __restrict__ out) {
  extern __shared__ char lds[];
  gemm_body<64, true>(lds, comb, wft, nullptr, NN, 192, 192, 0, fb, wp, bp, out, blockIdx.x);
}

extern "C" void kernel_launch(void* const* d_in, const int* in_sizes, int n_in, void* d_out,
                              int out_size, void* d_ws, size_t ws_size, hipStream_t stream) {
  const int Ds[3] = {1000, 1000, 500};
  const int H1 = 128, H2 = 64;

  char* p = (char*)d_ws;
  auto carve = [&](size_t bytes) {
    void* r = (void*)p;
    p += (bytes + 255) & ~(size_t)255;
    return r;
  };

  unsigned short* w1t[3];
  int kpad1[3];
  for (int b = 0; b < 3; ++b) {
    kpad1[b] = (Ds[b] + 31) & ~31;
    w1t[b] = (unsigned short*)carve((size_t)H1 * kpad1[b] * 2);
  }
  unsigned short* w2t[3];
  for (int b = 0; b < 3; ++b) w2t[b] = (unsigned short*)carve((size_t)H2 * 128 * 2);
  unsigned short* wft = (unsigned short*)carve((size_t)H2 * 192 * 2);

  unsigned* blockHist = (unsigned*)carve((size_t)3 * NEB * NBUK * 4);
  unsigned* cursors = (unsigned*)carve((size_t)3 * NEB * NBUK * 4);
  unsigned* totals = (unsigned*)carve((size_t)3 * NBUK * 4);
  unsigned* bucketBase = (unsigned*)carve((size_t)3 * NBUK * 4);
  int2* part = (int2*)carve((size_t)3 * NE * 8);
  int2* csr = (int2*)carve((size_t)3 * NE * 8);
  int* off3 = (int*)carve((size_t)3 * NN * 4);
  int* cnt3 = (int*)carve((size_t)3 * NN * 4);
  float* dinv3 = (float*)carve((size_t)3 * NN * 4);
  unsigned short *x1[3], *h1[3], *x2[3];
  for (int b = 0; b < 3; ++b) x1[b] = (unsigned short*)carve((size_t)NN * 128 * 2);
  for (int b = 0; b < 3; ++b) h1[b] = (unsigned short*)carve((size_t)NN * 128 * 2);
  for (int b = 0; b < 3; ++b) x2[b] = x1[b];  // alias: x1 dead after agg128
  unsigned short* comb = h1[0];               // alias: h1 dead after gemm2

  // ---- transposes (G1 weights tiled for DMA) ----
  TransArgs ta;
  int base = 0;
  const float* wsrc[7] = {(const float*)d_in[3],  (const float*)d_in[10], (const float*)d_in[17],
                          (const float*)d_in[5],  (const float*)d_in[12], (const float*)d_in[19],
                          (const float*)d_in[21]};
  unsigned short* wdst[7] = {w1t[0], w1t[1], w1t[2], w2t[0], w2t[1], w2t[2], wft};
  int wK[7] = {1000, 1000, 500, 128, 128, 128, 192};
  int wN[7] = {128, 128, 128, 64, 64, 64, 64};
  int wKp[7] = {1024, 1024, 512, 128, 128, 128, 192};
  int wTl[7] = {1, 1, 1, 0, 0, 0, 0};
  for (int s = 0; s < 7; ++s) {
    ta.d[s] = {wsrc[s], wdst[s], wK[s], wN[s], wKp[s], base, wTl[s]};
    base += wN[s] * wKp[s];
  }
  ta.total = base;
  transpose_all_kernel<<<(base + 255) / 256, 256, 0, stream>>>(ta);

  // ---- args ----
  BuildArgs ba;
  for (int b = 0; b < 3; ++b) {
    ba.ei[b] = (const int*)d_in[b * 7 + 1];
    ba.ew[b] = (const float*)d_in[b * 7 + 2];
  }
  ba.blockHist = blockHist;
  ba.cursors = cursors;
  ba.totals = totals;
  ba.bucketBase = bucketBase;
  ba.part = part;
  ba.off3 = off3;
  ba.cnt3 = cnt3;
  ba.dinv3 = dinv3;
  ba.csr = csr;

  G1Args g1;
  for (int b = 0; b < 3; ++b) {
    g1.A[b] = (const float*)d_in[b * 7 + 0];
    g1.B[b] = w1t[b];
    g1.C[b] = x1[b];
    g1.K[b] = Ds[b];
    g1.Kp[b] = kpad1[b];
  }

  const size_t G1LDS = 32768;                // DMA dbuf: A f32 16K + B bf16 16K
  const size_t G2LDS = (64 + 64) * 72 * 2;   // 18432
  const int TOT = 3 * GXc;                   // 2346
  const int SA = 800, SC = 646, SD1 = 450, SD2 = TOT - SA - SC - SD1;  // 450

  // ---- build + gemm1 slices (build blocks first) ----
  megaA_kernel<<<3 * NEB + SA, 256, G1LDS, stream>>>(ba, g1, 3 * NEB, 0);
  partB1_kernel<<<3 * NBUK, NEB, 0, stream>>>(ba);
  partB2_kernel<<<3, 256, 0, stream>>>(ba);
  megaC_kernel<<<3 * NEB + SC, 256, G1LDS, stream>>>(ba, g1, 3 * NEB, SA);
  megaD1_kernel<<<3 * NBUK + SD1, 256, G1LDS, stream>>>(ba, g1, 3 * NBUK, SA + SC);
  megaD2_kernel<<<3 * NBUK + SD2, 256, G1LDS, stream>>>(ba, g1, 3 * NBUK, SA + SC + SD1);

  // ---- agg128 x3 ----
  AggArgs aa;
  for (int b = 0; b < 3; ++b) {
    aa.x[b] = x1[b];
    aa.bias[b] = (const float*)d_in[b * 7 + 4];
    aa.out[b] = h1[b];
  }
  aa.dinv3 = dinv3;
  aa.cnt3 = cnt3;
  aa.off3 = off3;
  aa.csr = csr;
  agg128x3_kernel<<<3 * ABc, 256, 0, stream>>>(aa);

  // ---- gemm2 x3 ----
  G2Args g2;
  for (int b = 0; b < 3; ++b) {
    g2.A[b] = h1[b];
    g2.B[b] = w2t[b];
    g2.C[b] = x2[b];
  }
  gemm2x3_kernel<<<3 * GXc, 256, G2LDS, stream>>>(g2);

  // ---- agg64 x3 ----
  AggArgs bb;
  for (int b = 0; b < 3; ++b) {
    bb.x[b] = x2[b];
    bb.bias[b] = (const float*)d_in[b * 7 + 6];
    bb.out[b] = comb;
  }
  bb.out[0] = comb;
  bb.dinv3 = dinv3;
  bb.cnt3 = cnt3;
  bb.off3 = off3;
  bb.csr = csr;
  agg64x3_kernel<<<3 * AB64, 256, 0, stream>>>(bb);

  // ---- fuse + pred ----
  fuse_kernel<<<GXc, 256, G2LDS, stream>>>(comb, wft, (const float*)d_in[22],
                                           (const float*)d_in[23], (const float*)d_in[24],
                                           (float*)d_out);
}

// Round 15
// 420.812 us; speedup vs baseline: 1.0341x; 1.0341x over previous
//
#include <hip/hip_runtime.h>
#include <hip/hip_bf16.h>
#include <string.h>

typedef __attribute__((ext_vector_type(8))) short short8;
typedef __attribute__((ext_vector_type(4))) float f32x4;
typedef unsigned long long ull;

#define NN 50000
#define NE 600000
#define GXc 782    // ceil(50000/64)
#define ABc 12500  // agg128: 4 nodes/block
#define AB64 6250  // agg64: 8 nodes/block
#define NBUK 196
#define NEB 128
#define CHK 4688

__device__ __forceinline__ unsigned short f32_bf16(float f) {
  unsigned u = __float_as_uint(f);
  unsigned r = u + 0x7FFFu + ((u >> 16) & 1u);
  return (unsigned short)(r >> 16);
}
__device__ __forceinline__ float bf_lo(unsigned v) { return __uint_as_float(v << 16); }
__device__ __forceinline__ float bf_hi(unsigned v) { return __uint_as_float(v & 0xFFFF0000u); }

// ---------------- fused transpose of all 7 weights ----------------
// tiled=1 (G1 weights): elem = (k>>5)*4096 + ((k&31)>>3)*1024 + n*8 + (k&7)
//   -> per 32-k tile: granule-major [g][n][8], so LDS B reads are conflict-free
struct TransDesc { const float* src; unsigned short* dst; int K, Nn, Kpad, base, tiled; };
struct TransArgs { TransDesc d[7]; int total; };

__global__ void transpose_all_kernel(TransArgs a) {
  int idx = blockIdx.x * 256 + threadIdx.x;
  if (idx >= a.total) return;
  int s = 0;
#pragma unroll
  for (int q = 1; q < 7; ++q)
    if (idx >= a.d[q].base) s = q;
  TransDesc t = a.d[s];
  int off = idx - t.base;
  int n = off / t.Kpad, k = off % t.Kpad;
  float v = (k < t.K) ? t.src[(size_t)k * t.Nn + n] : 0.f;
  if (t.tiled)
    t.dst[(size_t)(k >> 5) * 4096 + ((k & 31) >> 3) * 1024 + n * 8 + (k & 7)] = f32_bf16(v);
  else
    t.dst[off] = f32_bf16(v);
}

// ---------- G1 GEMM: DMA-staged, BK=32, TRIPLE-buffer LDS + counted vmcnt ----------
// LDS (48 KB): A f32 [3][64][32] at 0 (3x8KB); B bf16 [3] granule-major at 24576 (3x8KB).
__device__ __forceinline__ void gemm1_dma_body(char* lds, const float* __restrict__ A,
                                               const unsigned short* __restrict__ BT,
                                               unsigned short* __restrict__ C, int M, int K,
                                               int Kpad, int bx) {
  const int tid = threadIdx.x;
  const int m0 = bx * 64;
  const int wave = tid >> 6, lane = tid & 63;
  const int wr = wave >> 1, wc = wave & 1;
  const int rowbase = wr * 32, colbase = wc * 64;
  const int lrow = lane & 15, lk = lane >> 4;
  const bool lastBlk = (m0 + 64 > M);
  const int nt = Kpad >> 5;

  char* AsBase = lds;
  char* BsBase = lds + 24576;

  f32x4 acc[2][4] = {};

  auto stageDMA = [&](int b, int kt) {
#pragma unroll
    for (int p = 0; p < 2; ++p) {
      int o = wave * 1024 + p * 4096 + lane * 16;
      int row = o >> 7;
      int g = (o >> 4) & 7;
      int scb = kt * 128 + ((g ^ (row & 7)) << 4);
      const char* gp = (const char*)(A + (size_t)(m0 + row) * K) + scb;
      char* lp = AsBase + b * 8192 + wave * 1024 + p * 4096;
      __builtin_amdgcn_global_load_lds((const __attribute__((address_space(1))) void*)gp,
                                       (__attribute__((address_space(3))) void*)lp, 16, 0, 0);
    }
#pragma unroll
    for (int p = 0; p < 2; ++p) {
      int o = wave * 1024 + p * 4096 + lane * 16;
      const char* gp = (const char*)BT + (size_t)kt * 8192 + o;
      char* lp = BsBase + b * 8192 + wave * 1024 + p * 4096;
      __builtin_amdgcn_global_load_lds((const __attribute__((address_space(1))) void*)gp,
                                       (__attribute__((address_space(3))) void*)lp, 16, 0, 0);
    }
  };

  auto stageReg = [&](int b, int kt) {  // guarded path, final row-block only
#pragma unroll
    for (int p = 0; p < 2; ++p) {
      int o = wave * 1024 + p * 4096 + lane * 16;
      int row = o >> 7;
      int g = (o >> 4) & 7;
      int c0 = kt * 32 + ((g ^ (row & 7)) << 2);
      int gr = m0 + row;
      float4 v = make_float4(0.f, 0.f, 0.f, 0.f);
      if (gr < M) {
        const float* sp = A + (size_t)gr * K + c0;
        if (c0 + 4 <= K) {
          v = *(const float4*)sp;
        } else {
          if (c0 + 0 < K) v.x = sp[0];
          if (c0 + 1 < K) v.y = sp[1];
          if (c0 + 2 < K) v.z = sp[2];
          if (c0 + 3 < K) v.w = sp[3];
        }
      }
      *(float4*)(AsBase + b * 8192 + o) = v;
    }
#pragma unroll
    for (int p = 0; p < 2; ++p) {
      int o = wave * 1024 + p * 4096 + lane * 16;
      short8 bv = *(const short8*)((const char*)BT + (size_t)kt * 8192 + o);
      *(short8*)(BsBase + b * 8192 + o) = bv;
    }
  };

  auto computeT = [&](int b) {
    short8 af[2], bfj[4];
#pragma unroll
    for (int i = 0; i < 2; ++i) {
      int row = rowbase + i * 16 + lrow;
      int r7 = row & 7;
      int g0 = (lk * 2 + 0) ^ r7;
      int g1 = (lk * 2 + 1) ^ r7;
      float4 a0 = *(const float4*)(AsBase + b * 8192 + row * 128 + (g0 << 4));
      float4 a1 = *(const float4*)(AsBase + b * 8192 + row * 128 + (g1 << 4));
      unsigned w0 = (unsigned)f32_bf16(a0.x) | ((unsigned)f32_bf16(a0.y) << 16);
      unsigned w1 = (unsigned)f32_bf16(a0.z) | ((unsigned)f32_bf16(a0.w) << 16);
      unsigned w2 = (unsigned)f32_bf16(a1.x) | ((unsigned)f32_bf16(a1.y) << 16);
      unsigned w3 = (unsigned)f32_bf16(a1.z) | ((unsigned)f32_bf16(a1.w) << 16);
      uint4 uu = make_uint4(w0, w1, w2, w3);
      af[i] = *reinterpret_cast<short8*>(&uu);
    }
#pragma unroll
    for (int j = 0; j < 4; ++j) {
      int n = colbase + j * 16 + lrow;
      bfj[j] = *(const short8*)(BsBase + b * 8192 + lk * 2048 + n * 16);
    }
#pragma unroll
    for (int i = 0; i < 2; ++i)
#pragma unroll
      for (int j = 0; j < 4; ++j)
        acc[i][j] = __builtin_amdgcn_mfma_f32_16x16x32_bf16(af[i], bfj[j], acc[i][j], 0, 0, 0);
  };

  if (!lastBlk) {
    stageDMA(0, 0);
    stageDMA(1, 1);
    asm volatile("s_waitcnt vmcnt(4)");
    __builtin_amdgcn_s_barrier();
    __builtin_amdgcn_sched_barrier(0);
    for (int kt = 0; kt < nt; ++kt) {
      int b = kt % 3;
      bool more = (kt + 2 < nt);
      if (more) stageDMA((kt + 2) % 3, kt + 2);
      computeT(b);
      if (kt + 1 < nt) {
        if (more)
          asm volatile("s_waitcnt vmcnt(4)");
        else
          asm volatile("s_waitcnt vmcnt(0)");
        __builtin_amdgcn_s_barrier();
        __builtin_amdgcn_sched_barrier(0);
      }
    }
  } else {
    stageReg(0, 0);
    __syncthreads();
    for (int kt = 0; kt < nt; ++kt) {
      int b = kt & 1;
      if (kt + 1 < nt) stageReg(b ^ 1, kt + 1);
      computeT(b);
      __syncthreads();
    }
  }

#pragma unroll
  for (int i = 0; i < 2; ++i)
#pragma unroll
    for (int j = 0; j < 4; ++j)
#pragma unroll
      for (int q = 0; q < 4; ++q) {
        int row = m0 + rowbase + i * 16 + lk * 4 + q;
        int col = colbase + j * 16 + lrow;
        if (row < M) C[(size_t)row * 128 + col] = f32_bf16(acc[i][j][q]);
      }
}

// ---------- register-staged GEMM body (gemm2 / fuse, bf16 A) ----------
template <int BN, bool PRED>
__device__ __forceinline__ void gemm_body(char* ldsraw, const unsigned short* __restrict__ Ah,
                                          const unsigned short* __restrict__ BT,
                                          unsigned short* __restrict__ C, int M, int K, int Kpad,
                                          int ldc, const float* fbias, const float* Wp,
                                          const float* bp, float* pout, int bx) {
  constexpr int BM = 64, BK = 64, LW = BK + 8;
  unsigned short* As = (unsigned short*)ldsraw;
  unsigned short* Bs = As + BM * LW;
  const int tid = threadIdx.x;
  const int m0 = bx * BM;
  const int wid = tid >> 6, lane = tid & 63;
  constexpr int FM = 1;
  constexpr int FN = 4;
  const int rowbase = wid * 16, colbase = 0;
  const int lrow = lane & 15, lk = lane >> 4;

  f32x4 acc[FM][FN] = {};
  short8 arh0[2], arh1[2];
  short8 brr0[BN / 32], brr1[BN / 32];

  const int nt = Kpad / BK;

  auto loadA = [&](auto& arhX, int k0) {
#pragma unroll
    for (int p = 0; p < 2; ++p) {
      int f = tid + p * 256;
      int row = f >> 3, c8 = f & 7;
      int gr = m0 + row;
      if (gr >= M) gr = M - 1;
      arhX[p] = *(const short8*)(Ah + (size_t)gr * K + k0 + c8 * 8);
    }
  };
  auto loadB = [&](auto& brrX, int k0) {
#pragma unroll
    for (int p = 0; p < BN / 32; ++p) {
      int f = tid + p * 256;
      int n = f >> 3, c8 = f & 7;
      brrX[p] = *(const short8*)(BT + (size_t)n * Kpad + k0 + c8 * 8);
    }
  };
  auto storeAB = [&](auto& arhX, auto& brrX) {
#pragma unroll
    for (int p = 0; p < 2; ++p) {
      int f = tid + p * 256;
      int row = f >> 3, c8 = f & 7;
      *reinterpret_cast<short8*>(&As[row * LW + c8 * 8]) = arhX[p];
    }
#pragma unroll
    for (int p = 0; p < BN / 32; ++p) {
      int f = tid + p * 256;
      int n = f >> 3, c8 = f & 7;
      *reinterpret_cast<short8*>(&Bs[n * LW + c8 * 8]) = brrX[p];
    }
  };
  auto compute = [&]() {
#pragma unroll
    for (int ks = 0; ks < 2; ++ks) {
      short8 af[FM], bfj[FN];
#pragma unroll
      for (int i = 0; i < FM; ++i)
        af[i] = *reinterpret_cast<const short8*>(
            &As[(rowbase + i * 16 + lrow) * LW + ks * 32 + lk * 8]);
#pragma unroll
      for (int j = 0; j < FN; ++j)
        bfj[j] = *reinterpret_cast<const short8*>(
            &Bs[(colbase + j * 16 + lrow) * LW + ks * 32 + lk * 8]);
#pragma unroll
      for (int i = 0; i < FM; ++i)
#pragma unroll
        for (int j = 0; j < FN; ++j)
          acc[i][j] = __builtin_amdgcn_mfma_f32_16x16x32_bf16(af[i], bfj[j], acc[i][j], 0, 0, 0);
    }
  };

  loadA(arh0, 0);
  loadB(brr0, 0);
  if (nt > 1) {
    loadA(arh1, BK);
    loadB(brr1, BK);
  }
  for (int kt = 0; kt < nt; kt += 2) {
    if (kt) __syncthreads();
    storeAB(arh0, brr0);
    __syncthreads();
    if (kt + 2 < nt) {
      loadA(arh0, (kt + 2) * BK);
      loadB(brr0, (kt + 2) * BK);
    }
    compute();
    if (kt + 1 < nt) {
      __syncthreads();
      storeAB(arh1, brr1);
      __syncthreads();
      if (kt + 3 < nt) {
        loadA(arh1, (kt + 3) * BK);
        loadB(brr1, (kt + 3) * BK);
      }
      compute();
    }
  }

  if (PRED) {
    float p0[4] = {0.f, 0.f, 0.f, 0.f}, p1[4] = {0.f, 0.f, 0.f, 0.f};
#pragma unroll
    for (int j = 0; j < FN; ++j) {
      int col = j * 16 + lrow;
      float w0 = Wp[col * 2], w1 = Wp[col * 2 + 1];
      float fb = fbias[col];
#pragma unroll
      for (int q = 0; q < 4; ++q) {
        float v = fmaxf(acc[0][j][q] + fb, 0.f);
        p0[q] += v * w0;
        p1[q] += v * w1;
      }
    }
#pragma unroll
    for (int o = 1; o < 16; o <<= 1) {
#pragma unroll
      for (int q = 0; q < 4; ++q) {
        p0[q] += __shfl_xor(p0[q], o);
        p1[q] += __shfl_xor(p1[q], o);
      }
    }
    if (lrow == 0) {
#pragma unroll
      for (int q = 0; q < 4; ++q) {
        int row = m0 + rowbase + lk * 4 + q;
        if (row < M) {
          pout[(size_t)row * 2 + 0] = p0[q] + bp[0];
          pout[(size_t)row * 2 + 1] = p1[q] + bp[1];
        }
      }
    }
  } else {
#pragma unroll
    for (int i = 0; i < FM; ++i)
#pragma unroll
      for (int j = 0; j < FN; ++j)
#pragma unroll
        for (int q = 0; q < 4; ++q) {
          int row = m0 + rowbase + i * 16 + lk * 4 + q;
          int col = colbase + j * 16 + lrow;
          if (row < M) C[(size_t)row * ldc + col] = f32_bf16(acc[i][j][q]);
        }
  }
}

// ================= atomic-free CSR build (bodies) =================
struct BuildArgs {
  const int* ei[3];
  const float* ew[3];
  unsigned* blockHist;
  unsigned* cursors;
  unsigned* totals;
  unsigned* bucketBase;
  int2* part;
  int* off3;
  int* cnt3;
  float* dinv3;
  int2* csr;
};

__device__ void partA_body(const BuildArgs& a, int bx) {
  int b = bx / NEB, blk = bx % NEB;
  __shared__ unsigned h[NBUK];
  for (int j = threadIdx.x; j < NBUK; j += 256) h[j] = 0;
  __syncthreads();
  const int* __restrict__ dstp = a.ei[b] + NE;
  int e0 = blk * CHK, e1 = e0 + CHK;
  if (e1 > NE) e1 = NE;
  for (int e = e0 + (int)threadIdx.x; e < e1; e += 256)
    atomicAdd(&h[(unsigned)dstp[e] >> 8], 1u);
  __syncthreads();
  unsigned* out = a.blockHist + (size_t)(b * NEB + blk) * NBUK;
  for (int j = threadIdx.x; j < NBUK; j += 256) out[j] = h[j];
}

__global__ void partB1_kernel(BuildArgs a) {
  int b = blockIdx.x / NBUK, k = blockIdx.x % NBUK;
  __shared__ unsigned s[NEB];
  int t = threadIdx.x;
  unsigned v = a.blockHist[(size_t)(b * NEB + t) * NBUK + k];
  s[t] = v;
  __syncthreads();
  for (int o = 1; o < NEB; o <<= 1) {
    unsigned u = (t >= o) ? s[t - o] : 0;
    __syncthreads();
    s[t] += u;
    __syncthreads();
  }
  a.cursors[(size_t)(b * NEB + t) * NBUK + k] = s[t] - v;
  if (t == NEB - 1) a.totals[b * NBUK + k] = s[t];
}

__global__ void partB2_kernel(BuildArgs a) {
  int b = blockIdx.x;
  __shared__ unsigned s[256];
  int t = threadIdx.x;
  unsigned v = (t < NBUK) ? a.totals[b * NBUK + t] : 0;
  s[t] = v;
  __syncthreads();
  for (int o = 1; o < 256; o <<= 1) {
    unsigned u = (t >= o) ? s[t - o] : 0;
    __syncthreads();
    s[t] += u;
    __syncthreads();
  }
  if (t < NBUK) a.bucketBase[b * NBUK + t] = s[t] - v;
}

__device__ void partC_body(const BuildArgs& a, int bx) {
  int b = bx / NEB, blk = bx % NEB;
  __shared__ unsigned cur[NBUK];
  for (int j = threadIdx.x; j < NBUK; j += 256)
    cur[j] = a.cursors[(size_t)(b * NEB + blk) * NBUK + j] + a.bucketBase[b * NBUK + j];
  __syncthreads();
  const int* __restrict__ srcp = a.ei[b];
  const int* __restrict__ dstp = srcp + NE;
  const float* __restrict__ ewp = a.ew[b];
  int2* __restrict__ out = a.part + (size_t)b * NE;
  int e0 = blk * CHK, e1 = e0 + CHK;
  if (e1 > NE) e1 = NE;
  for (int e = e0 + (int)threadIdx.x; e < e1; e += 256) {
    int d = dstp[e], s = srcp[e];
    float w = ewp[e];
    unsigned k = (unsigned)d >> 8;
    unsigned pos = atomicAdd(&cur[k], 1u);
    out[pos] = make_int2((int)(((unsigned)(d & 255) << 24) | (unsigned)s), __float_as_int(w));
  }
}

__device__ void partD1_body(const BuildArgs& a, int bx) {
  int b = bx / NBUK, k = bx % NBUK;
  __shared__ unsigned cnt[256];
  __shared__ float ws[256];
  int t = threadIdx.x;
  cnt[t] = 0;
  ws[t] = 0.f;
  __syncthreads();
  unsigned base = a.bucketBase[b * NBUK + k];
  unsigned total = a.totals[b * NBUK + k];
  const int2* __restrict__ pp = a.part + (size_t)b * NE + base;
  for (unsigned t2 = threadIdx.x; t2 < total; t2 += 256) {
    int2 pr = pp[t2];
    unsigned dl = (unsigned)pr.x >> 24;
    atomicAdd(&cnt[dl], 1u);
    atomicAdd(&ws[dl], __int_as_float(pr.y));
  }
  __syncthreads();
  unsigned v = cnt[t];
  float wv = ws[t];
  for (int o = 1; o < 256; o <<= 1) {
    unsigned u = (t >= o) ? cnt[t - o] : 0;
    __syncthreads();
    cnt[t] += u;
    __syncthreads();
  }
  int node = k * 256 + t;
  if (node < NN) {
    a.off3[b * NN + node] = (int)(base + cnt[t] - v);
    a.cnt3[b * NN + node] = (int)v;
    a.dinv3[b * NN + node] = rsqrtf(wv + 1.0f);
  }
}

__device__ void partD2_body(const BuildArgs& a, int bx) {
  int b = bx / NBUK, k = bx % NBUK;
  __shared__ unsigned cur[256];
  int t = threadIdx.x;
  int node = k * 256 + t;
  cur[t] = (node < NN) ? (unsigned)a.off3[b * NN + node] : 0u;
  __syncthreads();
  unsigned base = a.bucketBase[b * NBUK + k];
  unsigned total = a.totals[b * NBUK + k];
  const int2* __restrict__ pp = a.part + (size_t)b * NE + base;
  const float* __restrict__ dinvb = a.dinv3 + (size_t)b * NN;
  int2* __restrict__ out = a.csr + (size_t)b * NE;
  for (unsigned t2 = threadIdx.x; t2 < total; t2 += 256) {
    int2 pr = pp[t2];
    unsigned dl = (unsigned)pr.x >> 24;
    int s = pr.x & 0xFFFFFF;
    float w = __int_as_float(pr.y);
    unsigned pos = atomicAdd(&cur[dl], 1u);
    int d = k * 256 + (int)dl;
    float cw = dinvb[s] * w * dinvb[d];
    out[pos] = make_int2(s, __float_as_int(cw));
  }
}

// ================= mega kernels: build stage + gemm1 slice =================
struct G1Args {
  const float* A[3];
  const unsigned short* B[3];
  unsigned short* C[3];
  int K[3], Kp[3];
};

__device__ __forceinline__ void g1_dispatch(char* lds, const G1Args& g, int id) {
  int slot = id / GXc, b2 = id - slot * GXc;
  gemm1_dma_body(lds, g.A[slot], g.B[slot], g.C[slot], NN, g.K[slot], g.Kp[slot], b2);
}

__global__ __launch_bounds__(256) void megaA_kernel(BuildArgs ba, G1Args g1, int nbld, int base) {
  extern __shared__ char lds[];
  int bx = blockIdx.x;
  if (bx < nbld) { partA_body(ba, bx); return; }
  g1_dispatch(lds, g1, base + bx - nbld);
}
__global__ __launch_bounds__(256) void megaC_kernel(BuildArgs ba, G1Args g1, int nbld, int base) {
  extern __shared__ char lds[];
  int bx = blockIdx.x;
  if (bx < nbld) { partC_body(ba, bx); return; }
  g1_dispatch(lds, g1, base + bx - nbld);
}
__global__ __launch_bounds__(256) void megaD1_kernel(BuildArgs ba, G1Args g1, int nbld, int base) {
  extern __shared__ char lds[];
  int bx = blockIdx.x;
  if (bx < nbld) { partD1_body(ba, bx); return; }
  g1_dispatch(lds, g1, base + bx - nbld);
}
__global__ __launch_bounds__(256) void megaD2_kernel(BuildArgs ba, G1Args g1, int nbld, int base) {
  extern __shared__ char lds[];
  int bx = blockIdx.x;
  if (bx < nbld) { partD2_body(ba, bx); return; }
  g1_dispatch(lds, g1, base + bx - nbld);
}

// ================= aggregation (depth-4 pipelined gathers) =================
struct AggArgs {
  const unsigned short* x[3];
  const float* bias[3];
  unsigned short* out[3];
  const float* dinv3;
  const int* cnt3;
  const int* off3;
  const int2* csr;
};

__global__ __launch_bounds__(256) void agg128x3_kernel(AggArgs a) {
  int bx = blockIdx.x;
  int slot = bx / ABc, t = bx - slot * ABc;
  int i = (t << 2) + ((int)threadIdx.x >> 6);
  if (i >= NN) return;
  int lane = threadIdx.x & 63;
  const unsigned short* x = a.x[slot];
  float di = a.dinv3[(size_t)slot * NN + i];
  unsigned sv = *(const unsigned*)(x + (size_t)i * 128 + lane * 2);
  float w0s = di * di;
  float acc0 = bf_lo(sv) * w0s, acc1 = bf_hi(sv) * w0s;
  int cnt = a.cnt3[(size_t)slot * NN + i];
  const int2* cp = a.csr + (size_t)slot * NE + a.off3[slot * NN + i];

  int np = cnt & ~3;
  int2 e[4];
  unsigned v[4];
  if (np > 0) {
#pragma unroll
    for (int q = 0; q < 4; ++q) e[q] = cp[q];
#pragma unroll
    for (int q = 0; q < 4; ++q)
      v[q] = *(const unsigned*)(x + (size_t)e[q].x * 128 + lane * 2);
  }
  for (int t2 = 0; t2 < np; t2 += 4) {
    int2 en[4];
    unsigned vn[4];
    if (t2 + 4 < np) {
#pragma unroll
      for (int q = 0; q < 4; ++q) en[q] = cp[t2 + 4 + q];
#pragma unroll
      for (int q = 0; q < 4; ++q)
        vn[q] = *(const unsigned*)(x + (size_t)en[q].x * 128 + lane * 2);
    }
#pragma unroll
    for (int q = 0; q < 4; ++q) {
      float wt = __int_as_float(e[q].y);
      acc0 += bf_lo(v[q]) * wt;
      acc1 += bf_hi(v[q]) * wt;
    }
#pragma unroll
    for (int q = 0; q < 4; ++q) {
      e[q] = en[q];
      v[q] = vn[q];
    }
  }
  for (int t2 = np; t2 < cnt; ++t2) {
    int2 s0 = cp[t2];
    unsigned v0 = *(const unsigned*)(x + (size_t)s0.x * 128 + lane * 2);
    float wa = __int_as_float(s0.y);
    acc0 += bf_lo(v0) * wa;
    acc1 += bf_hi(v0) * wa;
  }
  acc0 = fmaxf(acc0 + a.bias[slot][lane * 2], 0.f);
  acc1 = fmaxf(acc1 + a.bias[slot][lane * 2 + 1], 0.f);
  unsigned o = (unsigned)f32_bf16(acc0) | ((unsigned)f32_bf16(acc1) << 16);
  *(unsigned*)(a.out[slot] + (size_t)i * 128 + lane * 2) = o;
}

__global__ __launch_bounds__(256) void agg64x3_kernel(AggArgs a) {
  int bx = blockIdx.x;
  int slot = bx / AB64, t = bx - slot * AB64;
  int i = (t << 3) + ((int)threadIdx.x >> 5);
  if (i >= NN) return;
  int l2 = (threadIdx.x & 31) * 2;
  const unsigned short* x = a.x[slot];
  float di = a.dinv3[(size_t)slot * NN + i];
  unsigned sv = *(const unsigned*)(x + (size_t)i * 64 + l2);
  float w0s = di * di;
  float acc0 = bf_lo(sv) * w0s, acc1 = bf_hi(sv) * w0s;
  int cnt = a.cnt3[(size_t)slot * NN + i];
  const int2* cp = a.csr + (size_t)slot * NE + a.off3[slot * NN + i];

  int np = cnt & ~3;
  int2 e[4];
  unsigned v[4];
  if (np > 0) {
#pragma unroll
    for (int q = 0; q < 4; ++q) e[q] = cp[q];
#pragma unroll
    for (int q = 0; q < 4; ++q)
      v[q] = *(const unsigned*)(x + (size_t)e[q].x * 64 + l2);
  }
  for (int t2 = 0; t2 < np; t2 += 4) {
    int2 en[4];
    unsigned vn[4];
    if (t2 + 4 < np) {
#pragma unroll
      for (int q = 0; q < 4; ++q) en[q] = cp[t2 + 4 + q];
#pragma unroll
      for (int q = 0; q < 4; ++q)
        vn[q] = *(const unsigned*)(x + (size_t)en[q].x * 64 + l2);
    }
#pragma unroll
    for (int q = 0; q < 4; ++q) {
      float wt = __int_as_float(e[q].y);
      acc0 += bf_lo(v[q]) * wt;
      acc1 += bf_hi(v[q]) * wt;
    }
#pragma unroll
    for (int q = 0; q < 4; ++q) {
      e[q] = en[q];
      v[q] = vn[q];
    }
  }
  for (int t2 = np; t2 < cnt; ++t2) {
    int2 s0 = cp[t2];
    unsigned v0 = *(const unsigned*)(x + (size_t)s0.x * 64 + l2);
    float wa = __int_as_float(s0.y);
    acc0 += bf_lo(v0) * wa;
    acc1 += bf_hi(v0) * wa;
  }
  acc0 = fmaxf(acc0 + a.bias[slot][l2], 0.f);
  acc1 = fmaxf(acc1 + a.bias[slot][l2 + 1], 0.f);
  unsigned o = (unsigned)f32_bf16(acc0) | ((unsigned)f32_bf16(acc1) << 16);
  *(unsigned*)(a.out[0] + (size_t)i * 192 + slot * 64 + l2) = o;
}

struct G2Args {
  const unsigned short* A[3];
  const unsigned short* B[3];
  unsigned short* C[3];
};

__global__ __launch_bounds__(256) void gemm2x3_kernel(G2Args a) {
  extern __shared__ char lds[];
  int slot = blockIdx.x / GXc, b2 = blockIdx.x - slot * GXc;
  gemm_body<64, false>(lds, a.A[slot], a.B[slot], a.C[slot], NN, 128, 128, 64, nullptr, nullptr,
                       nullptr, nullptr, b2);
}

__global__ __launch_bounds__(256) void fuse_kernel(const unsigned short* __restrict__ comb,
                                                   const unsigned short* __restrict__ wft,
                                                   const float* __restrict__ fb,
                                                   const float* __restrict__ wp,
                                                   const float* __restrict__ bp,
                                                   float* __restrict__ out) {
  extern __shared__ char lds[];
  gemm_body<64, true>(lds, comb, wft, nullptr, NN, 192, 192, 0, fb, wp, bp, out, blockIdx.x);
}

extern "C" void kernel_launch(void* const* d_in, const int* in_sizes, int n_in, void* d_out,
                              int out_size, void* d_ws, size_t ws_size, hipStream_t stream) {
  const int Ds[3] = {1000, 1000, 500};
  const int H1 = 128, H2 = 64;

  char* p = (char*)d_ws;
  auto carve = [&](size_t bytes) {
    void* r = (void*)p;
    p += (bytes + 255) & ~(size_t)255;
    return r;
  };

  unsigned short* w1t[3];
  int kpad1[3];
  for (int b = 0; b < 3; ++b) {
    kpad1[b] = (Ds[b] + 31) & ~31;
    w1t[b] = (unsigned short*)carve((size_t)H1 * kpad1[b] * 2);
  }
  unsigned short* w2t[3];
  for (int b = 0; b < 3; ++b) w2t[b] = (unsigned short*)carve((size_t)H2 * 128 * 2);
  unsigned short* wft = (unsigned short*)carve((size_t)H2 * 192 * 2);

  unsigned* blockHist = (unsigned*)carve((size_t)3 * NEB * NBUK * 4);
  unsigned* cursors = (unsigned*)carve((size_t)3 * NEB * NBUK * 4);
  unsigned* totals = (unsigned*)carve((size_t)3 * NBUK * 4);
  unsigned* bucketBase = (unsigned*)carve((size_t)3 * NBUK * 4);
  int2* part = (int2*)carve((size_t)3 * NE * 8);
  int2* csr = (int2*)carve((size_t)3 * NE * 8);
  int* off3 = (int*)carve((size_t)3 * NN * 4);
  int* cnt3 = (int*)carve((size_t)3 * NN * 4);
  float* dinv3 = (float*)carve((size_t)3 * NN * 4);
  unsigned short *x1[3], *h1[3], *x2[3];
  for (int b = 0; b < 3; ++b) x1[b] = (unsigned short*)carve((size_t)NN * 128 * 2);
  for (int b = 0; b < 3; ++b) h1[b] = (unsigned short*)carve((size_t)NN * 128 * 2);
  for (int b = 0; b < 3; ++b) x2[b] = x1[b];  // alias: x1 dead after agg128
  unsigned short* comb = h1[0];               // alias: h1 dead after gemm2

  // ---- transposes (G1 weights tiled granule-major for DMA + conflict-free reads) ----
  TransArgs ta;
  int base = 0;
  const float* wsrc[7] = {(const float*)d_in[3],  (const float*)d_in[10], (const float*)d_in[17],
                          (const float*)d_in[5],  (const float*)d_in[12], (const float*)d_in[19],
                          (const float*)d_in[21]};
  unsigned short* wdst[7] = {w1t[0], w1t[1], w1t[2], w2t[0], w2t[1], w2t[2], wft};
  int wK[7] = {1000, 1000, 500, 128, 128, 128, 192};
  int wN[7] = {128, 128, 128, 64, 64, 64, 64};
  int wKp[7] = {1024, 1024, 512, 128, 128, 128, 192};
  int wTl[7] = {1, 1, 1, 0, 0, 0, 0};
  for (int s = 0; s < 7; ++s) {
    ta.d[s] = {wsrc[s], wdst[s], wK[s], wN[s], wKp[s], base, wTl[s]};
    base += wN[s] * wKp[s];
  }
  ta.total = base;
  transpose_all_kernel<<<(base + 255) / 256, 256, 0, stream>>>(ta);

  // ---- args ----
  BuildArgs ba;
  for (int b = 0; b < 3; ++b) {
    ba.ei[b] = (const int*)d_in[b * 7 + 1];
    ba.ew[b] = (const float*)d_in[b * 7 + 2];
  }
  ba.blockHist = blockHist;
  ba.cursors = cursors;
  ba.totals = totals;
  ba.bucketBase = bucketBase;
  ba.part = part;
  ba.off3 = off3;
  ba.cnt3 = cnt3;
  ba.dinv3 = dinv3;
  ba.csr = csr;

  G1Args g1;
  for (int b = 0; b < 3; ++b) {
    g1.A[b] = (const float*)d_in[b * 7 + 0];
    g1.B[b] = w1t[b];
    g1.C[b] = x1[b];
    g1.K[b] = Ds[b];
    g1.Kp[b] = kpad1[b];
  }

  const size_t G1LDS = 49152;                // triple-buffer DMA: A 24K + B 24K
  const size_t G2LDS = (64 + 64) * 72 * 2;   // 18432
  const int TOT = 3 * GXc;                   // 2346
  const int SA = 800, SC = 646, SD1 = 450, SD2 = TOT - SA - SC - SD1;  // 450

  // ---- build + gemm1 slices (build blocks first) ----
  megaA_kernel<<<3 * NEB + SA, 256, G1LDS, stream>>>(ba, g1, 3 * NEB, 0);
  partB1_kernel<<<3 * NBUK, NEB, 0, stream>>>(ba);
  partB2_kernel<<<3, 256, 0, stream>>>(ba);
  megaC_kernel<<<3 * NEB + SC, 256, G1LDS, stream>>>(ba, g1, 3 * NEB, SA);
  megaD1_kernel<<<3 * NBUK + SD1, 256, G1LDS, stream>>>(ba, g1, 3 * NBUK, SA + SC);
  megaD2_kernel<<<3 * NBUK + SD2, 256, G1LDS, stream>>>(ba, g1, 3 * NBUK, SA + SC + SD1);

  // ---- agg128 x3 ----
  AggArgs aa;
  for (int b = 0; b < 3; ++b) {
    aa.x[b] = x1[b];
    aa.bias[b] = (const float*)d_in[b * 7 + 4];
    aa.out[b] = h1[b];
  }
  aa.dinv3 = dinv3;
  aa.cnt3 = cnt3;
  aa.off3 = off3;
  aa.csr = csr;
  agg128x3_kernel<<<3 * ABc, 256, 0, stream>>>(aa);

  // ---- gemm2 x3 ----
  G2Args g2;
  for (int b = 0; b < 3; ++b) {
    g2.A[b] = h1[b];
    g2.B[b] = w2t[b];
    g2.C[b] = x2[b];
  }
  gemm2x3_kernel<<<3 * GXc, 256, G2LDS, stream>>>(g2);

  // ---- agg64 x3 ----
  AggArgs bb;
  for (int b = 0; b < 3; ++b) {
    bb.x[b] = x2[b];
    bb.bias[b] = (const float*)d_in[b * 7 + 6];
    bb.out[b] = comb;
  }
  bb.out[0] = comb;
  bb.dinv3 = dinv3;
  bb.cnt3 = cnt3;
  bb.off3 = off3;
  bb.csr = csr;
  agg64x3_kernel<<<3 * AB64, 256, 0, stream>>>(bb);

  // ---- fuse + pred ----
  fuse_kernel<<<GXc, 256, G2LDS, stream>>>(comb, wft, (const float*)d_in[22],
                                           (const float*)d_in[23], (const float*)d_in[24],
                                           (float*)d_out);
}

// Round 16
// 377.838 us; speedup vs baseline: 1.1517x; 1.1137x over previous
//
#include <hip/hip_runtime.h>
#include <hip/hip_bf16.h>
#include <string.h>

typedef __attribute__((ext_vector_type(8))) short short8;
typedef __attribute__((ext_vector_type(4))) float f32x4;
typedef unsigned long long ull;

#define NN 50000
#define NE 600000
#define GXc 782    // ceil(50000/64)
#define ABc 12500  // agg128: 4 nodes/block
#define AB64 6250  // agg64: 8 nodes/block
#define NBUK 196
#define NEB 128
#define CHK 4688

__device__ __forceinline__ unsigned short f32_bf16(float f) {
  unsigned u = __float_as_uint(f);
  unsigned r = u + 0x7FFFu + ((u >> 16) & 1u);
  return (unsigned short)(r >> 16);
}
__device__ __forceinline__ float bf_lo(unsigned v) { return __uint_as_float(v << 16); }
__device__ __forceinline__ float bf_hi(unsigned v) { return __uint_as_float(v & 0xFFFF0000u); }

// ---------------- fused transpose of all 7 weights ----------------
struct TransDesc { const float* src; unsigned short* dst; int K, Nn, Kpad, base; };
struct TransArgs { TransDesc d[7]; int total; };

__global__ void transpose_all_kernel(TransArgs a) {
  int idx = blockIdx.x * 256 + threadIdx.x;
  if (idx >= a.total) return;
  int s = 0;
#pragma unroll
  for (int q = 1; q < 7; ++q)
    if (idx >= a.d[q].base) s = q;
  TransDesc t = a.d[s];
  int off = idx - t.base;
  int n = off / t.Kpad, k = off % t.Kpad;
  float v = (k < t.K) ? t.src[(size_t)k * t.Nn + n] : 0.f;
  t.dst[off] = f32_bf16(v);
}

// --- GEMM body: BK=64, depth-2 prefetch with STATIC buffer sets (rule #20 safe) ---
template <int BN, bool ABF16, bool PRED>
__device__ __forceinline__ void gemm_body(char* ldsraw, const void* __restrict__ Av,
                                          const unsigned short* __restrict__ BT,
                                          unsigned short* __restrict__ C, int M, int K, int Kpad,
                                          int ldc, const float* fbias, const float* Wp,
                                          const float* bp, float* pout, int bx) {
  constexpr int BM = 64, BK = 64, LW = BK + 8;  // LW=72
  unsigned short* As = (unsigned short*)ldsraw;
  unsigned short* Bs = As + BM * LW;
  const int tid = threadIdx.x;
  const int m0 = bx * BM;
  const int wid = tid >> 6, lane = tid & 63;
  constexpr int WC = (BN == 128) ? 2 : 1;
  constexpr int WTM = (BN == 128) ? 32 : 16;
  constexpr int FM = WTM / 16;
  constexpr int FN = 4;
  const int wr = wid / WC, wc = wid % WC;
  const int rowbase = wr * WTM, colbase = wc * 64;
  const int lrow = lane & 15, lk = lane >> 4;

  const float* Af = (const float*)Av;
  const unsigned short* Ah = (const unsigned short*)Av;

  f32x4 acc[FM][FN] = {};
  // statically named prefetch sets (no runtime-indexed arrays -> stays in VGPRs)
  float4 arf0[4], arf1[4];
  short8 arh0[2], arh1[2];
  short8 brr0[BN / 32], brr1[BN / 32];

  const int nt = Kpad / BK;

  auto loadA = [&](auto& arfX, auto& arhX, int k0) {
    if (ABF16) {
#pragma unroll
      for (int p = 0; p < 2; ++p) {
        int f = tid + p * 256;
        int row = f >> 3, c8 = f & 7;
        int gr = m0 + row;
        if (gr >= M) gr = M - 1;
        arhX[p] = *(const short8*)(Ah + (size_t)gr * K + k0 + c8 * 8);
      }
    } else {
#pragma unroll
      for (int p = 0; p < 4; ++p) {
        int f = tid + p * 256;
        int row = f >> 4, c4 = f & 15;
        int gr = m0 + row;
        if (gr >= M) gr = M - 1;
        int gk = k0 + c4 * 4;
        float4 v = make_float4(0.f, 0.f, 0.f, 0.f);
        const float* base = Af + (size_t)gr * K + gk;
        if (gk + 4 <= K) {
          v = *(const float4*)base;
        } else {
          if (gk + 0 < K) v.x = base[0];
          if (gk + 1 < K) v.y = base[1];
          if (gk + 2 < K) v.z = base[2];
          if (gk + 3 < K) v.w = base[3];
        }
        arfX[p] = v;
      }
    }
  };
  auto loadB = [&](auto& brrX, int k0) {
#pragma unroll
    for (int p = 0; p < BN / 32; ++p) {
      int f = tid + p * 256;
      int n = f >> 3, c8 = f & 7;
      brrX[p] = *(const short8*)(BT + (size_t)n * Kpad + k0 + c8 * 8);
    }
  };
  auto storeAB = [&](auto& arfX, auto& arhX, auto& brrX) {
    if (ABF16) {
#pragma unroll
      for (int p = 0; p < 2; ++p) {
        int f = tid + p * 256;
        int row = f >> 3, c8 = f & 7;
        *reinterpret_cast<short8*>(&As[row * LW + c8 * 8]) = arhX[p];
      }
    } else {
#pragma unroll
      for (int p = 0; p < 4; ++p) {
        int f = tid + p * 256;
        int row = f >> 4, c4 = f & 15;
        unsigned a0 = (unsigned)f32_bf16(arfX[p].x) | ((unsigned)f32_bf16(arfX[p].y) << 16);
        unsigned a1 = (unsigned)f32_bf16(arfX[p].z) | ((unsigned)f32_bf16(arfX[p].w) << 16);
        *reinterpret_cast<uint2*>(&As[row * LW + c4 * 4]) = make_uint2(a0, a1);
      }
    }
#pragma unroll
    for (int p = 0; p < BN / 32; ++p) {
      int f = tid + p * 256;
      int n = f >> 3, c8 = f & 7;
      *reinterpret_cast<short8*>(&Bs[n * LW + c8 * 8]) = brrX[p];
    }
  };
  auto compute = [&]() {
#pragma unroll
    for (int ks = 0; ks < 2; ++ks) {
      short8 af[FM], bfj[FN];
#pragma unroll
      for (int i = 0; i < FM; ++i)
        af[i] = *reinterpret_cast<const short8*>(
            &As[(rowbase + i * 16 + lrow) * LW + ks * 32 + lk * 8]);
#pragma unroll
      for (int j = 0; j < FN; ++j)
        bfj[j] = *reinterpret_cast<const short8*>(
            &Bs[(colbase + j * 16 + lrow) * LW + ks * 32 + lk * 8]);
#pragma unroll
      for (int i = 0; i < FM; ++i)
#pragma unroll
        for (int j = 0; j < FN; ++j)
          acc[i][j] = __builtin_amdgcn_mfma_f32_16x16x32_bf16(af[i], bfj[j], acc[i][j], 0, 0, 0);
    }
  };

  loadA(arf0, arh0, 0);
  loadB(brr0, 0);
  if (nt > 1) {
    loadA(arf1, arh1, BK);
    loadB(brr1, BK);
  }
  for (int kt = 0; kt < nt; kt += 2) {
    // even tile (set 0)
    if (kt) __syncthreads();
    storeAB(arf0, arh0, brr0);
    __syncthreads();
    if (kt + 2 < nt) {
      loadA(arf0, arh0, (kt + 2) * BK);
      loadB(brr0, (kt + 2) * BK);
    }
    compute();
    // odd tile (set 1)
    if (kt + 1 < nt) {
      __syncthreads();
      storeAB(arf1, arh1, brr1);
      __syncthreads();
      if (kt + 3 < nt) {
        loadA(arf1, arh1, (kt + 3) * BK);
        loadB(brr1, (kt + 3) * BK);
      }
      compute();
    }
  }

  if (PRED) {
    float p0[4] = {0.f, 0.f, 0.f, 0.f}, p1[4] = {0.f, 0.f, 0.f, 0.f};
#pragma unroll
    for (int j = 0; j < FN; ++j) {
      int col = j * 16 + lrow;
      float w0 = Wp[col * 2], w1 = Wp[col * 2 + 1];
      float fb = fbias[col];
#pragma unroll
      for (int q = 0; q < 4; ++q) {
        float v = fmaxf(acc[0][j][q] + fb, 0.f);
        p0[q] += v * w0;
        p1[q] += v * w1;
      }
    }
#pragma unroll
    for (int o = 1; o < 16; o <<= 1) {
#pragma unroll
      for (int q = 0; q < 4; ++q) {
        p0[q] += __shfl_xor(p0[q], o);
        p1[q] += __shfl_xor(p1[q], o);
      }
    }
    if (lrow == 0) {
#pragma unroll
      for (int q = 0; q < 4; ++q) {
        int row = m0 + rowbase + lk * 4 + q;
        if (row < M) {
          pout[(size_t)row * 2 + 0] = p0[q] + bp[0];
          pout[(size_t)row * 2 + 1] = p1[q] + bp[1];
        }
      }
    }
  } else {
#pragma unroll
    for (int i = 0; i < FM; ++i) {
#pragma unroll
      for (int j = 0; j < FN; ++j) {
#pragma unroll
        for (int q = 0; q < 4; ++q) {
          int row = m0 + rowbase + i * 16 + lk * 4 + q;
          int col = colbase + j * 16 + lrow;
          if (row < M) C[(size_t)row * ldc + col] = f32_bf16(acc[i][j][q]);
        }
      }
    }
  }
}

// ================= atomic-free CSR build (bodies) =================
struct BuildArgs {
  const int* ei[3];
  const float* ew[3];
  unsigned* blockHist;  // [3*NEB][NBUK]
  unsigned* cursors;    // [3*NEB][NBUK]
  unsigned* totals;     // [3][NBUK]
  unsigned* bucketBase; // [3][NBUK]
  int2* part;           // [3*NE]
  int* off3;
  int* cnt3;
  float* dinv3;
  int2* csr;
};

__device__ void partA_body(const BuildArgs& a, int bx) {
  int b = bx / NEB, blk = bx % NEB;
  __shared__ unsigned h[NBUK];
  for (int j = threadIdx.x; j < NBUK; j += 256) h[j] = 0;
  __syncthreads();
  const int* __restrict__ dstp = a.ei[b] + NE;
  int e0 = blk * CHK, e1 = e0 + CHK;
  if (e1 > NE) e1 = NE;
  for (int e = e0 + (int)threadIdx.x; e < e1; e += 256)
    atomicAdd(&h[(unsigned)dstp[e] >> 8], 1u);
  __syncthreads();
  unsigned* out = a.blockHist + (size_t)(b * NEB + blk) * NBUK;
  for (int j = threadIdx.x; j < NBUK; j += 256) out[j] = h[j];
}

__global__ void partB1_kernel(BuildArgs a) {
  int b = blockIdx.x / NBUK, k = blockIdx.x % NBUK;
  __shared__ unsigned s[NEB];
  int t = threadIdx.x;
  unsigned v = a.blockHist[(size_t)(b * NEB + t) * NBUK + k];
  s[t] = v;
  __syncthreads();
  for (int o = 1; o < NEB; o <<= 1) {
    unsigned u = (t >= o) ? s[t - o] : 0;
    __syncthreads();
    s[t] += u;
    __syncthreads();
  }
  a.cursors[(size_t)(b * NEB + t) * NBUK + k] = s[t] - v;
  if (t == NEB - 1) a.totals[b * NBUK + k] = s[t];
}

__global__ void partB2_kernel(BuildArgs a) {
  int b = blockIdx.x;
  __shared__ unsigned s[256];
  int t = threadIdx.x;
  unsigned v = (t < NBUK) ? a.totals[b * NBUK + t] : 0;
  s[t] = v;
  __syncthreads();
  for (int o = 1; o < 256; o <<= 1) {
    unsigned u = (t >= o) ? s[t - o] : 0;
    __syncthreads();
    s[t] += u;
    __syncthreads();
  }
  if (t < NBUK) a.bucketBase[b * NBUK + t] = s[t] - v;
}

__device__ void partC_body(const BuildArgs& a, int bx) {
  int b = bx / NEB, blk = bx % NEB;
  __shared__ unsigned cur[NBUK];
  for (int j = threadIdx.x; j < NBUK; j += 256)
    cur[j] = a.cursors[(size_t)(b * NEB + blk) * NBUK + j] + a.bucketBase[b * NBUK + j];
  __syncthreads();
  const int* __restrict__ srcp = a.ei[b];
  const int* __restrict__ dstp = srcp + NE;
  const float* __restrict__ ewp = a.ew[b];
  int2* __restrict__ out = a.part + (size_t)b * NE;
  int e0 = blk * CHK, e1 = e0 + CHK;
  if (e1 > NE) e1 = NE;
  for (int e = e0 + (int)threadIdx.x; e < e1; e += 256) {
    int d = dstp[e], s = srcp[e];
    float w = ewp[e];
    unsigned k = (unsigned)d >> 8;
    unsigned pos = atomicAdd(&cur[k], 1u);
    out[pos] = make_int2((int)(((unsigned)(d & 255) << 24) | (unsigned)s), __float_as_int(w));
  }
}

__device__ void partD1_body(const BuildArgs& a, int bx) {
  int b = bx / NBUK, k = bx % NBUK;
  __shared__ unsigned cnt[256];
  __shared__ float ws[256];
  int t = threadIdx.x;
  cnt[t] = 0;
  ws[t] = 0.f;
  __syncthreads();
  unsigned base = a.bucketBase[b * NBUK + k];
  unsigned total = a.totals[b * NBUK + k];
  const int2* __restrict__ pp = a.part + (size_t)b * NE + base;
  for (unsigned t2 = threadIdx.x; t2 < total; t2 += 256) {
    int2 pr = pp[t2];
    unsigned dl = (unsigned)pr.x >> 24;
    atomicAdd(&cnt[dl], 1u);
    atomicAdd(&ws[dl], __int_as_float(pr.y));
  }
  __syncthreads();
  unsigned v = cnt[t];
  float wv = ws[t];
  for (int o = 1; o < 256; o <<= 1) {
    unsigned u = (t >= o) ? cnt[t - o] : 0;
    __syncthreads();
    cnt[t] += u;
    __syncthreads();
  }
  int node = k * 256 + t;
  if (node < NN) {
    a.off3[b * NN + node] = (int)(base + cnt[t] - v);
    a.cnt3[b * NN + node] = (int)v;
    a.dinv3[b * NN + node] = rsqrtf(wv + 1.0f);
  }
}

__device__ void partD2_body(const BuildArgs& a, int bx) {
  int b = bx / NBUK, k = bx % NBUK;
  __shared__ unsigned cur[256];
  int t = threadIdx.x;
  int node = k * 256 + t;
  cur[t] = (node < NN) ? (unsigned)a.off3[b * NN + node] : 0u;
  __syncthreads();
  unsigned base = a.bucketBase[b * NBUK + k];
  unsigned total = a.totals[b * NBUK + k];
  const int2* __restrict__ pp = a.part + (size_t)b * NE + base;
  const float* __restrict__ dinvb = a.dinv3 + (size_t)b * NN;
  int2* __restrict__ out = a.csr + (size_t)b * NE;
  for (unsigned t2 = threadIdx.x; t2 < total; t2 += 256) {
    int2 pr = pp[t2];
    unsigned dl = (unsigned)pr.x >> 24;
    int s = pr.x & 0xFFFFFF;
    float w = __int_as_float(pr.y);
    unsigned pos = atomicAdd(&cur[dl], 1u);
    int d = k * 256 + (int)dl;
    float cw = dinvb[s] * w * dinvb[d];
    out[pos] = make_int2(s, __float_as_int(cw));
  }
}

// ================= mega kernels: build stage + gemm1 slice =================
struct G1Args {
  const float* A[3];
  const unsigned short* B[3];
  unsigned short* C[3];
  int K[3], Kp[3];
};

__device__ __forceinline__ void g1_dispatch(char* lds, const G1Args& g, int id) {
  int slot = id / GXc, b2 = id - slot * GXc;
  gemm_body<128, false, false>(lds, g.A[slot], g.B[slot], g.C[slot], NN, g.K[slot], g.Kp[slot],
                               128, nullptr, nullptr, nullptr, nullptr, b2);
}

__global__ __launch_bounds__(256) void megaA_kernel(BuildArgs ba, G1Args g1, int nbld, int base) {
  extern __shared__ char lds[];
  int bx = blockIdx.x;
  if (bx < nbld) { partA_body(ba, bx); return; }
  g1_dispatch(lds, g1, base + bx - nbld);
}
__global__ __launch_bounds__(256) void megaC_kernel(BuildArgs ba, G1Args g1, int nbld, int base) {
  extern __shared__ char lds[];
  int bx = blockIdx.x;
  if (bx < nbld) { partC_body(ba, bx); return; }
  g1_dispatch(lds, g1, base + bx - nbld);
}
__global__ __launch_bounds__(256) void megaD1_kernel(BuildArgs ba, G1Args g1, int nbld, int base) {
  extern __shared__ char lds[];
  int bx = blockIdx.x;
  if (bx < nbld) { partD1_body(ba, bx); return; }
  g1_dispatch(lds, g1, base + bx - nbld);
}
__global__ __launch_bounds__(256) void megaD2_kernel(BuildArgs ba, G1Args g1, int nbld, int base) {
  extern __shared__ char lds[];
  int bx = blockIdx.x;
  if (bx < nbld) { partD2_body(ba, bx); return; }
  g1_dispatch(lds, g1, base + bx - nbld);
}

// ================= aggregation (depth-4 pipelined gathers) =================
struct AggArgs {
  const unsigned short* x[3];
  const float* bias[3];
  unsigned short* out[3];
  const float* dinv3;
  const int* cnt3;
  const int* off3;
  const int2* csr;
};

__global__ __launch_bounds__(256) void agg128x3_kernel(AggArgs a) {
  int bx = blockIdx.x;
  int slot = bx / ABc, t = bx - slot * ABc;
  int i = (t << 2) + ((int)threadIdx.x >> 6);
  if (i >= NN) return;
  int lane = threadIdx.x & 63;
  const unsigned short* x = a.x[slot];
  float di = a.dinv3[(size_t)slot * NN + i];
  unsigned sv = *(const unsigned*)(x + (size_t)i * 128 + lane * 2);
  float w0s = di * di;
  float acc0 = bf_lo(sv) * w0s, acc1 = bf_hi(sv) * w0s;
  int cnt = a.cnt3[(size_t)slot * NN + i];
  const int2* cp = a.csr + (size_t)slot * NE + a.off3[slot * NN + i];

  int np = cnt & ~3;
  int2 e[4];
  unsigned v[4];
  if (np > 0) {
#pragma unroll
    for (int q = 0; q < 4; ++q) e[q] = cp[q];
#pragma unroll
    for (int q = 0; q < 4; ++q)
      v[q] = *(const unsigned*)(x + (size_t)e[q].x * 128 + lane * 2);
  }
  for (int t2 = 0; t2 < np; t2 += 4) {
    int2 en[4];
    unsigned vn[4];
    if (t2 + 4 < np) {
#pragma unroll
      for (int q = 0; q < 4; ++q) en[q] = cp[t2 + 4 + q];
#pragma unroll
      for (int q = 0; q < 4; ++q)
        vn[q] = *(const unsigned*)(x + (size_t)en[q].x * 128 + lane * 2);
    }
#pragma unroll
    for (int q = 0; q < 4; ++q) {
      float wt = __int_as_float(e[q].y);
      acc0 += bf_lo(v[q]) * wt;
      acc1 += bf_hi(v[q]) * wt;
    }
#pragma unroll
    for (int q = 0; q < 4; ++q) {
      e[q] = en[q];
      v[q] = vn[q];
    }
  }
  for (int t2 = np; t2 < cnt; ++t2) {
    int2 s0 = cp[t2];
    unsigned v0 = *(const unsigned*)(x + (size_t)s0.x * 128 + lane * 2);
    float wa = __int_as_float(s0.y);
    acc0 += bf_lo(v0) * wa;
    acc1 += bf_hi(v0) * wa;
  }
  acc0 = fmaxf(acc0 + a.bias[slot][lane * 2], 0.f);
  acc1 = fmaxf(acc1 + a.bias[slot][lane * 2 + 1], 0.f);
  unsigned o = (unsigned)f32_bf16(acc0) | ((unsigned)f32_bf16(acc1) << 16);
  *(unsigned*)(a.out[slot] + (size_t)i * 128 + lane * 2) = o;
}

// agg64: 32 lanes own one node, depth-4 pipeline
__global__ __launch_bounds__(256) void agg64x3_kernel(AggArgs a) {
  int bx = blockIdx.x;
  int slot = bx / AB64, t = bx - slot * AB64;
  int i = (t << 3) + ((int)threadIdx.x >> 5);
  if (i >= NN) return;
  int l2 = (threadIdx.x & 31) * 2;
  const unsigned short* x = a.x[slot];
  float di = a.dinv3[(size_t)slot * NN + i];
  unsigned sv = *(const unsigned*)(x + (size_t)i * 64 + l2);
  float w0s = di * di;
  float acc0 = bf_lo(sv) * w0s, acc1 = bf_hi(sv) * w0s;
  int cnt = a.cnt3[(size_t)slot * NN + i];
  const int2* cp = a.csr + (size_t)slot * NE + a.off3[slot * NN + i];

  int np = cnt & ~3;
  int2 e[4];
  unsigned v[4];
  if (np > 0) {
#pragma unroll
    for (int q = 0; q < 4; ++q) e[q] = cp[q];
#pragma unroll
    for (int q = 0; q < 4; ++q)
      v[q] = *(const unsigned*)(x + (size_t)e[q].x * 64 + l2);
  }
  for (int t2 = 0; t2 < np; t2 += 4) {
    int2 en[4];
    unsigned vn[4];
    if (t2 + 4 < np) {
#pragma unroll
      for (int q = 0; q < 4; ++q) en[q] = cp[t2 + 4 + q];
#pragma unroll
      for (int q = 0; q < 4; ++q)
        vn[q] = *(const unsigned*)(x + (size_t)en[q].x * 64 + l2);
    }
#pragma unroll
    for (int q = 0; q < 4; ++q) {
      float wt = __int_as_float(e[q].y);
      acc0 += bf_lo(v[q]) * wt;
      acc1 += bf_hi(v[q]) * wt;
    }
#pragma unroll
    for (int q = 0; q < 4; ++q) {
      e[q] = en[q];
      v[q] = vn[q];
    }
  }
  for (int t2 = np; t2 < cnt; ++t2) {
    int2 s0 = cp[t2];
    unsigned v0 = *(const unsigned*)(x + (size_t)s0.x * 64 + l2);
    float wa = __int_as_float(s0.y);
    acc0 += bf_lo(v0) * wa;
    acc1 += bf_hi(v0) * wa;
  }
  acc0 = fmaxf(acc0 + a.bias[slot][l2], 0.f);
  acc1 = fmaxf(acc1 + a.bias[slot][l2 + 1], 0.f);
  unsigned o = (unsigned)f32_bf16(acc0) | ((unsigned)f32_bf16(acc1) << 16);
  *(unsigned*)(a.out[0] + (size_t)i * 192 + slot * 64 + l2) = o;
}

struct G2Args {
  const unsigned short* A[3];
  const unsigned short* B[3];
  unsigned short* C[3];
};

__global__ __launch_bounds__(256) void gemm2x3_kernel(G2Args a) {
  extern __shared__ char lds[];
  int slot = blockIdx.x / GXc, b2 = blockIdx.x - slot * GXc;
  gemm_body<64, true, false>(lds, a.A[slot], a.B[slot], a.C[slot], NN, 128, 128, 64, nullptr,
                             nullptr, nullptr, nullptr, b2);
}

__global__ __launch_bounds__(256) void fuse_kernel(const unsigned short* __restrict__ comb,
                                                   const unsigned short* __restrict__ wft,
                                                   const float* __restrict__ fb,
                                                   const float* __restrict__ wp,
                                                   const float* __restrict__ bp,
                                                   float* __restrict__ out) {
  extern __shared__ char lds[];
  gemm_body<64, true, true>(lds, comb, wft, nullptr, NN, 192, 192, 0, fb, wp, bp, out,
                            blockIdx.x);
}

extern "C" void kernel_launch(void* const* d_in, const int* in_sizes, int n_in, void* d_out,
                              int out_size, void* d_ws, size_t ws_size, hipStream_t stream) {
  const int Ds[3] = {1000, 1000, 500};
  const int H1 = 128, H2 = 64;

  char* p = (char*)d_ws;
  auto carve = [&](size_t bytes) {
    void* r = (void*)p;
    p += (bytes + 255) & ~(size_t)255;
    return r;
  };

  unsigned short* w1t[3];
  int kpad1[3];
  for (int b = 0; b < 3; ++b) {
    kpad1[b] = (Ds[b] + 63) & ~63;
    w1t[b] = (unsigned short*)carve((size_t)H1 * kpad1[b] * 2);
  }
  unsigned short* w2t[3];
  for (int b = 0; b < 3; ++b) w2t[b] = (unsigned short*)carve((size_t)H2 * 128 * 2);
  unsigned short* wft = (unsigned short*)carve((size_t)H2 * 192 * 2);

  unsigned* blockHist = (unsigned*)carve((size_t)3 * NEB * NBUK * 4);
  unsigned* cursors = (unsigned*)carve((size_t)3 * NEB * NBUK * 4);
  unsigned* totals = (unsigned*)carve((size_t)3 * NBUK * 4);
  unsigned* bucketBase = (unsigned*)carve((size_t)3 * NBUK * 4);
  int2* part = (int2*)carve((size_t)3 * NE * 8);
  int2* csr = (int2*)carve((size_t)3 * NE * 8);
  int* off3 = (int*)carve((size_t)3 * NN * 4);
  int* cnt3 = (int*)carve((size_t)3 * NN * 4);
  float* dinv3 = (float*)carve((size_t)3 * NN * 4);
  unsigned short *x1[3], *h1[3], *x2[3];
  for (int b = 0; b < 3; ++b) x1[b] = (unsigned short*)carve((size_t)NN * 128 * 2);
  for (int b = 0; b < 3; ++b) h1[b] = (unsigned short*)carve((size_t)NN * 128 * 2);
  for (int b = 0; b < 3; ++b) x2[b] = x1[b];  // alias: x1 dead after agg128
  unsigned short* comb = h1[0];               // alias: h1 dead after gemm2

  // ---- transposes ----
  TransArgs ta;
  int base = 0;
  const float* wsrc[7] = {(const float*)d_in[3],  (const float*)d_in[10], (const float*)d_in[17],
                          (const float*)d_in[5],  (const float*)d_in[12], (const float*)d_in[19],
                          (const float*)d_in[21]};
  unsigned short* wdst[7] = {w1t[0], w1t[1], w1t[2], w2t[0], w2t[1], w2t[2], wft};
  int wK[7] = {1000, 1000, 500, 128, 128, 128, 192};
  int wN[7] = {128, 128, 128, 64, 64, 64, 64};
  int wKp[7] = {1024, 1024, 512, 128, 128, 128, 192};
  for (int s = 0; s < 7; ++s) {
    ta.d[s] = {wsrc[s], wdst[s], wK[s], wN[s], wKp[s], base};
    base += wN[s] * wKp[s];
  }
  ta.total = base;
  transpose_all_kernel<<<(base + 255) / 256, 256, 0, stream>>>(ta);

  // ---- args ----
  BuildArgs ba;
  for (int b = 0; b < 3; ++b) {
    ba.ei[b] = (const int*)d_in[b * 7 + 1];
    ba.ew[b] = (const float*)d_in[b * 7 + 2];
  }
  ba.blockHist = blockHist;
  ba.cursors = cursors;
  ba.totals = totals;
  ba.bucketBase = bucketBase;
  ba.part = part;
  ba.off3 = off3;
  ba.cnt3 = cnt3;
  ba.dinv3 = dinv3;
  ba.csr = csr;

  G1Args g1;
  for (int b = 0; b < 3; ++b) {
    g1.A[b] = (const float*)d_in[b * 7 + 0];
    g1.B[b] = w1t[b];
    g1.C[b] = x1[b];
    g1.K[b] = Ds[b];
    g1.Kp[b] = kpad1[b];
  }

  const size_t G1LDS = (64 + 128) * 72 * 2;  // 27648
  const size_t G2LDS = (64 + 64) * 72 * 2;   // 18432
  const int TOT = 3 * GXc;                   // 2346
  const int SA = 1000, SC = 700, SD1 = 323, SD2 = TOT - SA - SC - SD1;  // 323

  // ---- build + gemm1 slices (build blocks first) ----
  megaA_kernel<<<3 * NEB + SA, 256, G1LDS, stream>>>(ba, g1, 3 * NEB, 0);
  partB1_kernel<<<3 * NBUK, NEB, 0, stream>>>(ba);
  partB2_kernel<<<3, 256, 0, stream>>>(ba);
  megaC_kernel<<<3 * NEB + SC, 256, G1LDS, stream>>>(ba, g1, 3 * NEB, SA);
  megaD1_kernel<<<3 * NBUK + SD1, 256, G1LDS, stream>>>(ba, g1, 3 * NBUK, SA + SC);
  megaD2_kernel<<<3 * NBUK + SD2, 256, G1LDS, stream>>>(ba, g1, 3 * NBUK, SA + SC + SD1);

  // ---- agg128 x3 ----
  AggArgs aa;
  for (int b = 0; b < 3; ++b) {
    aa.x[b] = x1[b];
    aa.bias[b] = (const float*)d_in[b * 7 + 4];
    aa.out[b] = h1[b];
  }
  aa.dinv3 = dinv3;
  aa.cnt3 = cnt3;
  aa.off3 = off3;
  aa.csr = csr;
  agg128x3_kernel<<<3 * ABc, 256, 0, stream>>>(aa);

  // ---- gemm2 x3 ----
  G2Args g2;
  for (int b = 0; b < 3; ++b) {
    g2.A[b] = h1[b];
    g2.B[b] = w2t[b];
    g2.C[b] = x2[b];
  }
  gemm2x3_kernel<<<3 * GXc, 256, G2LDS, stream>>>(g2);

  // ---- agg64 x3 ----
  AggArgs bb;
  for (int b = 0; b < 3; ++b) {
    bb.x[b] = x2[b];
    bb.bias[b] = (const float*)d_in[b * 7 + 6];
    bb.out[b] = comb;
  }
  bb.out[0] = comb;
  bb.dinv3 = dinv3;
  bb.cnt3 = cnt3;
  bb.off3 = off3;
  bb.csr = csr;
  agg64x3_kernel<<<3 * AB64, 256, 0, stream>>>(bb);

  // ---- fuse + pred ----
  fuse_kernel<<<GXc, 256, G2LDS, stream>>>(comb, wft, (const float*)d_in[22],
                                           (const float*)d_in[23], (const float*)d_in[24],
                                           (float*)d_out);
}